// Round 1
// baseline (3770.139 us; speedup 1.0000x reference)
//
#include <hip/hip_runtime.h>

static constexpr int BATCH = 512;
static constexpr int TT    = 1020;   // conv output length (1024 - 5 + 1)
static constexpr int MM    = BATCH * TT;  // 522240 rows for xg GEMMs

// ---- fast device nonlinearities (1-ulp hw exp2/rcp; fine vs 1.76e-3 budget) ----
__device__ __forceinline__ float fsig(float x) {
  float e = __builtin_amdgcn_exp2f(x * -1.442695041f);
  return __builtin_amdgcn_rcpf(1.0f + e);
}
__device__ __forceinline__ float ftanh(float x) {
  float e = __builtin_amdgcn_exp2f(x * 2.885390082f); // 2^(2x*log2e) = e^(2x)
  return 1.0f - 2.0f * __builtin_amdgcn_rcpf(e + 1.0f);
}

// =====================================================================
// conv1d valid, K=5: x[512][128][1024] (*) w[128][128][5] + b -> c[512][128][1020]
// block: 256 thr computes [32 co][256 l] for one b; LDS-staged x and w chunks.
// =====================================================================
__global__ __launch_bounds__(256) void conv_kernel(
    const float* __restrict__ x, const float* __restrict__ w,
    const float* __restrict__ bias, float* __restrict__ c) {
  __shared__ float xs[32][260];    // 32 ci x 260 l (256 + 4 halo)
  __shared__ float wsm[32][164];   // 32 co x (ci*5+k), padded pitch
  const int b   = blockIdx.z;
  const int co0 = blockIdx.y * 32;
  const int l0  = blockIdx.x * 256;
  const int tid = threadIdx.x;
  const int tl  = tid & 31;   // l-group: l = l0 + tl*8 + j
  const int tc  = tid >> 5;   // co-group: co = co0 + tc*4 + cc

  float acc[4][8];
#pragma unroll
  for (int i = 0; i < 4; ++i)
#pragma unroll
    for (int j = 0; j < 8; ++j) acc[i][j] = 0.f;

  for (int ci0 = 0; ci0 < 128; ci0 += 32) {
    __syncthreads();
    // --- stage x chunk: rows ci = tid>>3, 8 threads per row ---
    {
      const int ci = tid >> 3;
      const int j0 = tid & 7;
      const float* xrow = x + ((size_t)b * 128 + ci0 + ci) * 1024;
      for (int j = j0; j < 65; j += 8) {
        const int l = l0 + 4 * j;
        float4 v;
        if (l + 3 < 1024) v = *(const float4*)(xrow + l);
        else { v.x = 0.f; v.y = 0.f; v.z = 0.f; v.w = 0.f; }  // only fully-OOB case occurs
        *(float4*)&xs[ci][4 * j] = v;
      }
    }
    // --- stage w chunk: 32co x 32ci x 5 = 5120 elems, coalesced-ish reads ---
    for (int i = tid; i < 5120; i += 256) {
      const int co = i / 160;
      const int r  = i - co * 160;             // ci*5+k
      wsm[co][r] = w[(size_t)(co0 + co) * 640 + ci0 * 5 + r];
    }
    __syncthreads();
    // --- compute ---
    for (int ci = 0; ci < 32; ++ci) {
      float xv[12];
      const float4 v0 = *(const float4*)&xs[ci][tl * 8];
      const float4 v1 = *(const float4*)&xs[ci][tl * 8 + 4];
      const float4 v2 = *(const float4*)&xs[ci][tl * 8 + 8];
      xv[0]=v0.x; xv[1]=v0.y; xv[2]=v0.z; xv[3]=v0.w;
      xv[4]=v1.x; xv[5]=v1.y; xv[6]=v1.z; xv[7]=v1.w;
      xv[8]=v2.x; xv[9]=v2.y; xv[10]=v2.z; xv[11]=v2.w;
#pragma unroll
      for (int k = 0; k < 5; ++k)
#pragma unroll
        for (int cc = 0; cc < 4; ++cc) {
          const float wv = wsm[tc * 4 + cc][ci * 5 + k];
#pragma unroll
          for (int j = 0; j < 8; ++j)
            acc[cc][j] = fmaf(wv, xv[k + j], acc[cc][j]);
        }
    }
  }
  // --- store (guard l < 1020) ---
#pragma unroll
  for (int cc = 0; cc < 4; ++cc) {
    const int co = co0 + tc * 4 + cc;
    const float bv = bias[co];
    float* crow = c + (size_t)b * 130560 + (size_t)co * TT;
    const int lbase = l0 + tl * 8;
#pragma unroll
    for (int j = 0; j < 8; ++j) {
      const int l = lbase + j;
      if (l < TT) crow[l] = acc[cc][j] + bv;
    }
  }
}

// =====================================================================
// xg GEMM: A[MM][K] @ W[N][K]^T + (bih+bhh), output TRANSPOSED per batch:
// xgT[b][n][t]  (so the LSTM streams each gate contiguously over t).
// block: 64m x 64n, thread 4x4, K staged in chunks of <=64 through LDS.
// =====================================================================
template <int K>
__global__ __launch_bounds__(256) void gemm_xg(
    const float* __restrict__ A, const float* __restrict__ W,
    const float* __restrict__ bih, const float* __restrict__ bhh,
    float* __restrict__ xgT, const int Ntot) {
  constexpr int KC = (K > 64) ? 64 : K;
  constexpr int LITEMS = (16 * KC) / 256 > 0 ? (16 * KC) / 256 : 1; // float4s per thread
  __shared__ float At[KC][68];
  __shared__ float Wt[KC][68];
  const int m0 = blockIdx.x * 64;
  const int n0 = blockIdx.y * 64;
  const int tid = threadIdx.x;
  const int tn = tid & 15;   // n = n0 + tn*4 + j
  const int tm = tid >> 4;   // m = m0 + tm*4 + i

  float acc[4][4];
#pragma unroll
  for (int i = 0; i < 4; ++i)
#pragma unroll
    for (int j = 0; j < 4; ++j) acc[i][j] = 0.f;

  for (int kc = 0; kc < K; kc += KC) {
    __syncthreads();
#pragma unroll
    for (int it = 0; it < LITEMS; ++it) {
      const int i  = tid + it * 256;
      const int r  = i / (KC / 4);
      const int c4 = i % (KC / 4);
      const float4 v = *(const float4*)(A + (size_t)(m0 + r) * K + kc + c4 * 4);
      At[c4 * 4 + 0][r] = v.x; At[c4 * 4 + 1][r] = v.y;
      At[c4 * 4 + 2][r] = v.z; At[c4 * 4 + 3][r] = v.w;
    }
#pragma unroll
    for (int it = 0; it < LITEMS; ++it) {
      const int i  = tid + it * 256;
      const int r  = i / (KC / 4);
      const int c4 = i % (KC / 4);
      const float4 v = *(const float4*)(W + (size_t)(n0 + r) * K + kc + c4 * 4);
      Wt[c4 * 4 + 0][r] = v.x; Wt[c4 * 4 + 1][r] = v.y;
      Wt[c4 * 4 + 2][r] = v.z; Wt[c4 * 4 + 3][r] = v.w;
    }
    __syncthreads();
#pragma unroll 8
    for (int k = 0; k < KC; ++k) {
      const float4 av = *(const float4*)&At[k][tm * 4];
      const float4 wv = *(const float4*)&Wt[k][tn * 4];
      const float a[4] = {av.x, av.y, av.z, av.w};
      const float wr[4] = {wv.x, wv.y, wv.z, wv.w};
#pragma unroll
      for (int i = 0; i < 4; ++i)
#pragma unroll
        for (int j = 0; j < 4; ++j)
          acc[i][j] = fmaf(a[i], wr[j], acc[i][j]);
    }
  }
  // epilogue: bias + transposed scatter (exact magic div by 1020)
  float bv[4];
#pragma unroll
  for (int j = 0; j < 4; ++j)
    bv[j] = bih[n0 + tn * 4 + j] + bhh[n0 + tn * 4 + j];
#pragma unroll
  for (int i = 0; i < 4; ++i) {
    const int m  = m0 + tm * 4 + i;
    const int bb = (int)(((unsigned long long)m * 4311810306ULL) >> 42); // m/1020 exact
    const int t  = m - bb * TT;
    float* dst = xgT + ((size_t)bb * Ntot + n0 + tn * 4) * TT + t;
#pragma unroll
    for (int j = 0; j < 4; ++j) dst[(size_t)j * TT] = acc[i][j] + bv[j];
  }
}

// =====================================================================
// LSTM recurrence: one wave per batch element. Gate order i,f,g,o.
// H=32: lane holds gates {lane, lane+64}; H=16: lane holds gate {lane}.
// Whh rows live in VGPRs; h broadcast via readlane; gate transpose via shfl_xor.
// xgT[b][g][t] streamed as float4 with a 4-step-ahead prefetch ring.
// =====================================================================
template <int H, bool FINAL>
__global__ __launch_bounds__(64) void lstm_kernel(
    const float* __restrict__ xgT, const float* __restrict__ Whh,
    float* __restrict__ hout) {
  constexpr int G   = 4 * H;
  constexpr int GPL = G / 64;  // 2 for H=32, 1 for H=16
  const int b    = blockIdx.x;
  const int lane = threadIdx.x;
  const int g0 = lane;
  const int g1 = lane + 64;

  float w0[H];
  float w1[GPL == 2 ? H : 1];
#pragma unroll
  for (int k = 0; k < H; ++k) {
    w0[k] = Whh[g0 * H + k];
    if constexpr (GPL == 2) w1[k] = Whh[g1 * H + k];
  }

  const float* p0 = xgT + ((size_t)b * G + g0) * TT;
  const float* p1 = xgT + ((size_t)b * G + (GPL == 2 ? g1 : g0)) * TT;

  float h = 0.f, c = 0.f;
  float4 cur0, cur1 = {0.f, 0.f, 0.f, 0.f};
  float4 nxt0 = *(const float4*)(p0);
  float4 nxt1 = {0.f, 0.f, 0.f, 0.f};
  if constexpr (GPL == 2) nxt1 = *(const float4*)(p1);

  for (int t4 = 0; t4 < TT; t4 += 4) {
    cur0 = nxt0;
    if constexpr (GPL == 2) cur1 = nxt1;
    const int tn = t4 + 4;
    if (tn < TT) {                         // prefetch 4 steps ahead (~1200 cyc)
      nxt0 = *(const float4*)(p0 + tn);
      if constexpr (GPL == 2) nxt1 = *(const float4*)(p1 + tn);
    }
#pragma unroll
    for (int s = 0; s < 4; ++s) {
      float acc0 = ((const float*)&cur0)[s];
      float acc1 = 0.f;
      if constexpr (GPL == 2) acc1 = ((const float*)&cur1)[s];
      // recurrent matvec: broadcast h[k] from lane k (SALU readlane, co-issues)
#pragma unroll
      for (int k = 0; k < H; ++k) {
        const float hk =
            __uint_as_float(__builtin_amdgcn_readlane(__float_as_uint(h), k));
        acc0 = fmaf(w0[k], hk, acc0);
        if constexpr (GPL == 2) acc1 = fmaf(w1[k], hk, acc1);
      }
      // gather i,f,g,o raw gate values to every lane (duplicated across groups)
      float iraw, fraw, graw, oraw;
      if constexpr (H == 32) {
        const float r0 = __shfl_xor(acc0, 32, 64);
        const float r1 = __shfl_xor(acc1, 32, 64);
        const bool hi = lane >= 32;
        iraw = hi ? r0 : acc0;
        fraw = hi ? acc0 : r0;
        graw = hi ? r1 : acc1;
        oraw = hi ? acc1 : r1;
      } else {
        const float x1 = __shfl_xor(acc0, 16, 64);
        const float x2 = __shfl_xor(acc0, 32, 64);
        const float x3 = __shfl_xor(acc0, 48, 64);
        const int q = lane >> 4;          // gate group of this lane
        const float t0 = (q & 1) ? x1 : acc0;  // even group of own pair
        const float t1 = (q & 1) ? acc0 : x1;  // odd group of own pair
        const float u0 = (q & 1) ? x3 : x2;    // even group of other pair
        const float u1 = (q & 1) ? x2 : x3;    // odd group of other pair
        const bool hi2 = q >= 2;
        iraw = hi2 ? u0 : t0;
        fraw = hi2 ? u1 : t1;
        graw = hi2 ? t0 : u0;
        oraw = hi2 ? t1 : u1;
      }
      const float ig = fsig(iraw);
      const float fg = fsig(fraw);
      const float gg = ftanh(graw);
      const float og = fsig(oraw);
      c = fmaf(fg, c, ig * gg);
      h = og * ftanh(c);
      if constexpr (!FINAL) {
        if (lane < H) hout[((size_t)b * TT + (t4 + s)) * H + lane] = h;
      } else {
        if (t4 + s == TT - 1 && lane < H) hout[b * H + lane] = h;
      }
    }
  }
}

// =====================================================================
extern "C" void kernel_launch(void* const* d_in, const int* in_sizes, int n_in,
                              void* d_out, int out_size, void* d_ws, size_t ws_size,
                              hipStream_t stream) {
  const float* x      = (const float*)d_in[0];
  const float* conv_w = (const float*)d_in[1];
  const float* conv_b = (const float*)d_in[2];
  const float* Wih1   = (const float*)d_in[3];
  const float* Whh1   = (const float*)d_in[4];
  const float* bih1   = (const float*)d_in[5];
  const float* bhh1   = (const float*)d_in[6];
  const float* Wih2   = (const float*)d_in[7];
  const float* Whh2   = (const float*)d_in[8];
  const float* bih2   = (const float*)d_in[9];
  const float* bhh2   = (const float*)d_in[10];
  const float* Wih3   = (const float*)d_in[11];
  const float* Whh3   = (const float*)d_in[12];
  const float* bih3   = (const float*)d_in[13];
  const float* bhh3   = (const float*)d_in[14];
  float* out = (float*)d_out;
  float* ws  = (float*)d_ws;

  // workspace layout (floats); regions reused once dead:
  float* c    = ws;                    // 66,846,720  : conv out == seq (flat view)
  float* xgT1 = ws + 66846720;         // 66,846,720  : layer-1 gates, transposed
  float* h1   = ws + 133693440;        // 16,711,680  : layer-1 hidden
  float* xgT2 = c;                     // 33,423,360  : reuse conv region
  float* h2   = h1;                    //  8,355,840  : reuse h1 region
  float* xgT3 = xgT1;                  // 66,846,720  : reuse xgT1 region
  // total footprint: 601.6 MB

  conv_kernel<<<dim3(4, 4, BATCH), 256, 0, stream>>>(x, conv_w, conv_b, c);
  // seq is c reinterpreted as [B*1020][128] (the reference's .view quirk)
  gemm_xg<128><<<dim3(MM / 64, 2), 256, 0, stream>>>(c, Wih1, bih1, bhh1, xgT1, 128);
  lstm_kernel<32, false><<<BATCH, 64, 0, stream>>>(xgT1, Whh1, h1);
  gemm_xg<32><<<dim3(MM / 64, 1), 256, 0, stream>>>(h1, Wih2, bih2, bhh2, xgT2, 64);
  lstm_kernel<16, false><<<BATCH, 64, 0, stream>>>(xgT2, Whh2, h2);
  gemm_xg<16><<<dim3(MM / 64, 2), 256, 0, stream>>>(h2, Wih3, bih3, bhh3, xgT3, 128);
  lstm_kernel<32, true><<<BATCH, 64, 0, stream>>>(xgT3, Whh3, out);
}

// Round 2
// 3647.507 us; speedup vs baseline: 1.0336x; 1.0336x over previous
//
#include <hip/hip_runtime.h>

static constexpr int BATCH = 512;
static constexpr int TT    = 1020;   // conv output length (1024 - 5 + 1)
static constexpr int MM    = BATCH * TT;  // 522240 rows for xg GEMMs

// ---- fast device nonlinearities (1-ulp hw exp2/rcp; fine vs 1.76e-3 budget) ----
__device__ __forceinline__ float fsig(float x) {
  float e = __builtin_amdgcn_exp2f(x * -1.442695041f);
  return __builtin_amdgcn_rcpf(1.0f + e);
}
__device__ __forceinline__ float ftanh(float x) {
  float e = __builtin_amdgcn_exp2f(x * 2.885390082f); // e^(2x)
  return 1.0f - 2.0f * __builtin_amdgcn_rcpf(e + 1.0f);
}

// =====================================================================
// conv1d valid, K=5: x[512][128][1024] (*) w[128][128][5] + b -> c[512][128][1020]
// Conflict-free mapping: lane owns 4 consecutive l (b128 LDS reads = lane ->
// consecutive 16B segments), wave owns 8 co (w reads wave-uniform broadcast).
// Staging writes are b32 with <=2-way bank aliasing (free).
// =====================================================================
__global__ __launch_bounds__(256) void conv_kernel(
    const float* __restrict__ x, const float* __restrict__ w,
    const float* __restrict__ bias, float* __restrict__ c) {
  __shared__ float xs[32][260];    // pitch 260 floats = 1040 B (16B aligned rows)
  __shared__ float wsm[32][160];   // [co][ci*5+k]; reads are broadcast -> no pad
  const int b   = blockIdx.z;
  const int co0 = blockIdx.y * 32;
  const int l0  = blockIdx.x * 256;
  const int tid = threadIdx.x;
  const int lid = tid & 63;   // l = l0 + lid*4 + j   (j = 0..3)
  const int wid = tid >> 6;   // co = co0 + wid*8 + cc (wave-uniform)

  float acc[8][4];
#pragma unroll
  for (int i = 0; i < 8; ++i)
#pragma unroll
    for (int j = 0; j < 4; ++j) acc[i][j] = 0.f;

  for (int ci0 = 0; ci0 < 128; ci0 += 32) {
    __syncthreads();
    // --- stage x chunk: thread (ci=tid>>3, j0=tid&7), b32 writes, <=2-way ---
    {
      const int ci = tid >> 3;
      const int j0 = tid & 7;
      const float* xrow = x + ((size_t)b * 128 + ci0 + ci) * 1024 + l0;
      for (int j = j0; j < 260; j += 8)
        xs[ci][j] = (l0 + j < 1024) ? xrow[j] : 0.f;
    }
    // --- stage w chunk: 32co x 160 = 5120 elems ---
    for (int it = 0; it < 20; ++it) {
      const int i  = tid + it * 256;
      const int co = i / 160;
      const int r  = i - co * 160;             // ci*5+k
      wsm[co][r] = w[(size_t)(co0 + co) * 640 + ci0 * 5 + r];
    }
    __syncthreads();
    // --- compute: per ci, 2 conflict-free b128 reads + 40 broadcast w reads ---
    for (int ci = 0; ci < 32; ++ci) {
      float xv[8];
      *(float4*)&xv[0] = *(const float4*)&xs[ci][lid * 4];
      *(float4*)&xv[4] = *(const float4*)&xs[ci][lid * 4 + 4];
#pragma unroll
      for (int k = 0; k < 5; ++k)
#pragma unroll
        for (int cc = 0; cc < 8; ++cc) {
          const float wv = wsm[wid * 8 + cc][ci * 5 + k];
#pragma unroll
          for (int j = 0; j < 4; ++j)
            acc[cc][j] = fmaf(wv, xv[k + j], acc[cc][j]);
        }
    }
  }
  // --- store: float4 per co row; l multiple of 4, TT%4==0 -> whole-vec guard ---
  const int l = l0 + lid * 4;
  if (l < TT) {
#pragma unroll
    for (int cc = 0; cc < 8; ++cc) {
      const int co = co0 + wid * 8 + cc;
      const float bv = bias[co];
      float* crow = c + (size_t)b * 130560 + (size_t)co * TT;
      float4 st;
      st.x = acc[cc][0] + bv; st.y = acc[cc][1] + bv;
      st.z = acc[cc][2] + bv; st.w = acc[cc][3] + bv;
      *(float4*)(crow + l) = st;
    }
  }
}

// =====================================================================
// xg GEMM: A[MM][K] @ W[N][K]^T + (bih+bhh), output TRANSPOSED per batch:
// xgT[b][n][t]  (so the LSTM streams each gate contiguously over t).
// block: 64m x 64n, thread 4x4, K staged in chunks of <=64 through LDS.
// =====================================================================
template <int K>
__global__ __launch_bounds__(256) void gemm_xg(
    const float* __restrict__ A, const float* __restrict__ W,
    const float* __restrict__ bih, const float* __restrict__ bhh,
    float* __restrict__ xgT, const int Ntot) {
  constexpr int KC = (K > 64) ? 64 : K;
  constexpr int LITEMS = (16 * KC) / 256 > 0 ? (16 * KC) / 256 : 1; // float4s per thread
  __shared__ float At[KC][68];
  __shared__ float Wt[KC][68];
  const int m0 = blockIdx.x * 64;
  const int n0 = blockIdx.y * 64;
  const int tid = threadIdx.x;
  const int tn = tid & 15;   // n = n0 + tn*4 + j
  const int tm = tid >> 4;   // m = m0 + tm*4 + i

  float acc[4][4];
#pragma unroll
  for (int i = 0; i < 4; ++i)
#pragma unroll
    for (int j = 0; j < 4; ++j) acc[i][j] = 0.f;

  for (int kc = 0; kc < K; kc += KC) {
    __syncthreads();
#pragma unroll
    for (int it = 0; it < LITEMS; ++it) {
      const int i  = tid + it * 256;
      const int r  = i / (KC / 4);
      const int c4 = i % (KC / 4);
      const float4 v = *(const float4*)(A + (size_t)(m0 + r) * K + kc + c4 * 4);
      At[c4 * 4 + 0][r] = v.x; At[c4 * 4 + 1][r] = v.y;
      At[c4 * 4 + 2][r] = v.z; At[c4 * 4 + 3][r] = v.w;
    }
#pragma unroll
    for (int it = 0; it < LITEMS; ++it) {
      const int i  = tid + it * 256;
      const int r  = i / (KC / 4);
      const int c4 = i % (KC / 4);
      const float4 v = *(const float4*)(W + (size_t)(n0 + r) * K + kc + c4 * 4);
      Wt[c4 * 4 + 0][r] = v.x; Wt[c4 * 4 + 1][r] = v.y;
      Wt[c4 * 4 + 2][r] = v.z; Wt[c4 * 4 + 3][r] = v.w;
    }
    __syncthreads();
#pragma unroll 8
    for (int k = 0; k < KC; ++k) {
      const float4 av = *(const float4*)&At[k][tm * 4];
      const float4 wv = *(const float4*)&Wt[k][tn * 4];
      const float a[4] = {av.x, av.y, av.z, av.w};
      const float wr[4] = {wv.x, wv.y, wv.z, wv.w};
#pragma unroll
      for (int i = 0; i < 4; ++i)
#pragma unroll
        for (int j = 0; j < 4; ++j)
          acc[i][j] = fmaf(a[i], wr[j], acc[i][j]);
    }
  }
  // epilogue: bias + transposed scatter (exact magic div by 1020)
  float bv[4];
#pragma unroll
  for (int j = 0; j < 4; ++j)
    bv[j] = bih[n0 + tn * 4 + j] + bhh[n0 + tn * 4 + j];
#pragma unroll
  for (int i = 0; i < 4; ++i) {
    const int m  = m0 + tm * 4 + i;
    const int bb = (int)(((unsigned long long)m * 4311810306ULL) >> 42); // m/1020 exact
    const int t  = m - bb * TT;
    float* dst = xgT + ((size_t)bb * Ntot + n0 + tn * 4) * TT + t;
#pragma unroll
    for (int j = 0; j < 4; ++j) dst[(size_t)j * TT] = acc[i][j] + bv[j];
  }
}

// =====================================================================
// LSTM recurrence: one wave per batch element. Gate order i,f,g,o.
// H=32: lane holds gates {lane, lane+64}; H=16: lane holds gate {lane}.
// Whh rows live in VGPRs; h broadcast via readlane; gate transpose via shfl_xor.
// Recurrent matvec uses 4 independent partial accumulators to cut the
// exposed FMA dependency chain from H*4cyc to (H/4)*4 + 8 cyc.
// =====================================================================
template <int H, bool FINAL>
__global__ __launch_bounds__(64) void lstm_kernel(
    const float* __restrict__ xgT, const float* __restrict__ Whh,
    float* __restrict__ hout) {
  constexpr int G   = 4 * H;
  constexpr int GPL = G / 64;  // 2 for H=32, 1 for H=16
  constexpr int KG  = H / 4;   // k-group size
  const int b    = blockIdx.x;
  const int lane = threadIdx.x;
  const int g0 = lane;
  const int g1 = lane + 64;

  float w0[H];
  float w1[GPL == 2 ? H : 1];
#pragma unroll
  for (int k = 0; k < H; ++k) {
    w0[k] = Whh[g0 * H + k];
    if constexpr (GPL == 2) w1[k] = Whh[g1 * H + k];
  }

  const float* p0 = xgT + ((size_t)b * G + g0) * TT;
  const float* p1 = xgT + ((size_t)b * G + (GPL == 2 ? g1 : g0)) * TT;

  float h = 0.f, c = 0.f;
  float4 cur0, cur1 = {0.f, 0.f, 0.f, 0.f};
  float4 nxt0 = *(const float4*)(p0);
  float4 nxt1 = {0.f, 0.f, 0.f, 0.f};
  if constexpr (GPL == 2) nxt1 = *(const float4*)(p1);

  for (int t4 = 0; t4 < TT; t4 += 4) {
    cur0 = nxt0;
    if constexpr (GPL == 2) cur1 = nxt1;
    const int tn = t4 + 4;
    if (tn < TT) {                         // prefetch 4 steps ahead (~1200 cyc)
      nxt0 = *(const float4*)(p0 + tn);
      if constexpr (GPL == 2) nxt1 = *(const float4*)(p1 + tn);
    }
#pragma unroll
    for (int s = 0; s < 4; ++s) {
      // recurrent matvec with 4-way split accumulators (short dep chains)
      float q0[4], q1[4];
      q0[0] = ((const float*)&cur0)[s]; q0[1] = 0.f; q0[2] = 0.f; q0[3] = 0.f;
      if constexpr (GPL == 2) {
        q1[0] = ((const float*)&cur1)[s]; q1[1] = 0.f; q1[2] = 0.f; q1[3] = 0.f;
      }
#pragma unroll
      for (int g = 0; g < 4; ++g)
#pragma unroll
        for (int k8 = 0; k8 < KG; ++k8) {
          const int k = g * KG + k8;
          const float hk =
              __uint_as_float(__builtin_amdgcn_readlane(__float_as_uint(h), k));
          q0[g] = fmaf(w0[k], hk, q0[g]);
          if constexpr (GPL == 2) q1[g] = fmaf(w1[k], hk, q1[g]);
        }
      const float acc0 = (q0[0] + q0[1]) + (q0[2] + q0[3]);
      float acc1 = 0.f;
      if constexpr (GPL == 2) acc1 = (q1[0] + q1[1]) + (q1[2] + q1[3]);

      // gather i,f,g,o raw gate values to every lane (duplicated across groups)
      float iraw, fraw, graw, oraw;
      if constexpr (H == 32) {
        const float r0 = __shfl_xor(acc0, 32, 64);
        const float r1 = __shfl_xor(acc1, 32, 64);
        const bool hi = lane >= 32;
        iraw = hi ? r0 : acc0;
        fraw = hi ? acc0 : r0;
        graw = hi ? r1 : acc1;
        oraw = hi ? acc1 : r1;
      } else {
        const float x1 = __shfl_xor(acc0, 16, 64);
        const float x2 = __shfl_xor(acc0, 32, 64);
        const float x3 = __shfl_xor(acc0, 48, 64);
        const int q = lane >> 4;          // gate group of this lane
        const float t0 = (q & 1) ? x1 : acc0;  // even group of own pair
        const float t1 = (q & 1) ? acc0 : x1;  // odd group of own pair
        const float u0 = (q & 1) ? x3 : x2;    // even group of other pair
        const float u1 = (q & 1) ? x2 : x3;    // odd group of other pair
        const bool hi2 = q >= 2;
        iraw = hi2 ? u0 : t0;
        fraw = hi2 ? u1 : t1;
        graw = hi2 ? t0 : u0;
        oraw = hi2 ? t1 : u1;
      }
      const float ig = fsig(iraw);
      const float fg = fsig(fraw);
      const float gg = ftanh(graw);
      const float og = fsig(oraw);
      c = fmaf(fg, c, ig * gg);
      h = og * ftanh(c);
      if constexpr (!FINAL) {
        if (lane < H) hout[((size_t)b * TT + (t4 + s)) * H + lane] = h;
      } else {
        if (t4 + s == TT - 1 && lane < H) hout[b * H + lane] = h;
      }
    }
  }
}

// =====================================================================
extern "C" void kernel_launch(void* const* d_in, const int* in_sizes, int n_in,
                              void* d_out, int out_size, void* d_ws, size_t ws_size,
                              hipStream_t stream) {
  const float* x      = (const float*)d_in[0];
  const float* conv_w = (const float*)d_in[1];
  const float* conv_b = (const float*)d_in[2];
  const float* Wih1   = (const float*)d_in[3];
  const float* Whh1   = (const float*)d_in[4];
  const float* bih1   = (const float*)d_in[5];
  const float* bhh1   = (const float*)d_in[6];
  const float* Wih2   = (const float*)d_in[7];
  const float* Whh2   = (const float*)d_in[8];
  const float* bih2   = (const float*)d_in[9];
  const float* bhh2   = (const float*)d_in[10];
  const float* Wih3   = (const float*)d_in[11];
  const float* Whh3   = (const float*)d_in[12];
  const float* bih3   = (const float*)d_in[13];
  const float* bhh3   = (const float*)d_in[14];
  float* out = (float*)d_out;
  float* ws  = (float*)d_ws;

  // workspace layout (floats); regions reused once dead:
  float* c    = ws;                    // 66,846,720  : conv out == seq (flat view)
  float* xgT1 = ws + 66846720;         // 66,846,720  : layer-1 gates, transposed
  float* h1   = ws + 133693440;        // 16,711,680  : layer-1 hidden
  float* xgT2 = c;                     // 33,423,360  : reuse conv region
  float* h2   = h1;                    //  8,355,840  : reuse h1 region
  float* xgT3 = xgT1;                  // 66,846,720  : reuse xgT1 region
  // total footprint: 601.6 MB

  conv_kernel<<<dim3(4, 4, BATCH), 256, 0, stream>>>(x, conv_w, conv_b, c);
  // seq is c reinterpreted as [B*1020][128] (the reference's .view quirk)
  gemm_xg<128><<<dim3(MM / 64, 2), 256, 0, stream>>>(c, Wih1, bih1, bhh1, xgT1, 128);
  lstm_kernel<32, false><<<BATCH, 64, 0, stream>>>(xgT1, Whh1, h1);
  gemm_xg<32><<<dim3(MM / 64, 1), 256, 0, stream>>>(h1, Wih2, bih2, bhh2, xgT2, 64);
  lstm_kernel<16, false><<<BATCH, 64, 0, stream>>>(xgT2, Whh2, h2);
  gemm_xg<16><<<dim3(MM / 64, 2), 256, 0, stream>>>(h2, Wih3, bih3, bhh3, xgT3, 128);
  lstm_kernel<32, true><<<BATCH, 64, 0, stream>>>(xgT3, Whh3, out);
}

// Round 3
// 2904.734 us; speedup vs baseline: 1.2979x; 1.2557x over previous
//
#include <hip/hip_runtime.h>

static constexpr int BATCH = 512;
static constexpr int TT    = 1020;   // conv output length (1024 - 5 + 1)
static constexpr int MM    = BATCH * TT;  // 522240 rows for xg GEMMs

// ---- fast device nonlinearities (1-ulp hw exp2/rcp; fine vs 1.76e-3 budget) ----
__device__ __forceinline__ float fsig(float x) {
  float e = __builtin_amdgcn_exp2f(x * -1.442695041f);
  return __builtin_amdgcn_rcpf(1.0f + e);
}
__device__ __forceinline__ float ftanh(float x) {
  float e = __builtin_amdgcn_exp2f(x * 2.885390082f); // e^(2x)
  return 1.0f - 2.0f * __builtin_amdgcn_rcpf(e + 1.0f);
}

// =====================================================================
// conv1d valid, K=5: x[512][128][1024] (*) w[128][128][5] + b -> c[512][128][1020]
// R2 finding: kernel was LDS-pipe bound (40 wsm broadcast reads/ci = 87% of
// LDS cycles). Fix: w reads use fully-scalar addressing -> s_load into SGPRs
// (SMEM pipe), wsm LDS buffer deleted. LDS per ci = 2 ds_read_b128 only.
// =====================================================================
__global__ __launch_bounds__(256, 4) void conv_kernel(
    const float* __restrict__ x, const float* __restrict__ w,
    const float* __restrict__ bias, float* __restrict__ c) {
  __shared__ float xs[32][260];    // 33,280 B -> 4 blocks/CU
  const int b   = blockIdx.z;
  const int co0 = blockIdx.y * 32;
  const int l0  = blockIdx.x * 256;
  const int tid = threadIdx.x;
  const int lid = tid & 63;   // l = l0 + lid*4 + j   (j = 0..3)
  // wave-uniform co group, forced into SGPR so w addressing stays scalar
  const int wid = __builtin_amdgcn_readfirstlane(tid >> 6);
  const float* wbase = w + (size_t)(co0 + wid * 8) * 640;

  float acc[8][4];
#pragma unroll
  for (int i = 0; i < 8; ++i)
#pragma unroll
    for (int j = 0; j < 4; ++j) acc[i][j] = 0.f;

  for (int ci0 = 0; ci0 < 128; ci0 += 32) {
    __syncthreads();
    // --- stage x chunk: thread (ci=tid>>3, j0=tid&7), b32 writes, <=2-way ---
    {
      const int ci = tid >> 3;
      const int j0 = tid & 7;
      const float* xrow = x + ((size_t)b * 128 + ci0 + ci) * 1024 + l0;
      for (int j = j0; j < 260; j += 8)
        xs[ci][j] = (l0 + j < 1024) ? xrow[j] : 0.f;
    }
    __syncthreads();
    // --- compute: per ci, 2 conflict-free b128 LDS reads; w via s_load ---
#pragma unroll 2
    for (int ci = 0; ci < 32; ++ci) {
      float xv[8];
      *(float4*)&xv[0] = *(const float4*)&xs[ci][lid * 4];
      *(float4*)&xv[4] = *(const float4*)&xs[ci][lid * 4 + 4];
      float wv[8][5];   // wave-uniform -> SGPRs via s_load
#pragma unroll
      for (int cc = 0; cc < 8; ++cc)
#pragma unroll
        for (int k = 0; k < 5; ++k)
          wv[cc][k] = wbase[(size_t)cc * 640 + (ci0 + ci) * 5 + k];
#pragma unroll
      for (int k = 0; k < 5; ++k)
#pragma unroll
        for (int cc = 0; cc < 8; ++cc)
#pragma unroll
          for (int j = 0; j < 4; ++j)
            acc[cc][j] = fmaf(wv[cc][k], xv[k + j], acc[cc][j]);
    }
  }
  // --- store: float4 per co row; l multiple of 4, TT%4==0 -> whole-vec guard ---
  const int l = l0 + lid * 4;
  if (l < TT) {
#pragma unroll
    for (int cc = 0; cc < 8; ++cc) {
      const int co = co0 + wid * 8 + cc;
      const float bv = bias[co];   // uniform -> s_load
      float* crow = c + (size_t)b * 130560 + (size_t)co * TT;
      float4 st;
      st.x = acc[cc][0] + bv; st.y = acc[cc][1] + bv;
      st.z = acc[cc][2] + bv; st.w = acc[cc][3] + bv;
      *(float4*)(crow + l) = st;
    }
  }
}

// =====================================================================
// xg GEMM: A[MM][K] @ W[N][K]^T + (bih+bhh), output TRANSPOSED per batch:
// xgT[b][n][t]  (so the LSTM streams each gate contiguously over t).
// block: 64m x 64n, thread 4x4, K staged in chunks of <=64 through LDS.
// =====================================================================
template <int K>
__global__ __launch_bounds__(256) void gemm_xg(
    const float* __restrict__ A, const float* __restrict__ W,
    const float* __restrict__ bih, const float* __restrict__ bhh,
    float* __restrict__ xgT, const int Ntot) {
  constexpr int KC = (K > 64) ? 64 : K;
  constexpr int LITEMS = (16 * KC) / 256 > 0 ? (16 * KC) / 256 : 1; // float4s per thread
  __shared__ float At[KC][68];
  __shared__ float Wt[KC][68];
  const int m0 = blockIdx.x * 64;
  const int n0 = blockIdx.y * 64;
  const int tid = threadIdx.x;
  const int tn = tid & 15;   // n = n0 + tn*4 + j
  const int tm = tid >> 4;   // m = m0 + tm*4 + i

  float acc[4][4];
#pragma unroll
  for (int i = 0; i < 4; ++i)
#pragma unroll
    for (int j = 0; j < 4; ++j) acc[i][j] = 0.f;

  for (int kc = 0; kc < K; kc += KC) {
    __syncthreads();
#pragma unroll
    for (int it = 0; it < LITEMS; ++it) {
      const int i  = tid + it * 256;
      const int r  = i / (KC / 4);
      const int c4 = i % (KC / 4);
      const float4 v = *(const float4*)(A + (size_t)(m0 + r) * K + kc + c4 * 4);
      At[c4 * 4 + 0][r] = v.x; At[c4 * 4 + 1][r] = v.y;
      At[c4 * 4 + 2][r] = v.z; At[c4 * 4 + 3][r] = v.w;
    }
#pragma unroll
    for (int it = 0; it < LITEMS; ++it) {
      const int i  = tid + it * 256;
      const int r  = i / (KC / 4);
      const int c4 = i % (KC / 4);
      const float4 v = *(const float4*)(W + (size_t)(n0 + r) * K + kc + c4 * 4);
      Wt[c4 * 4 + 0][r] = v.x; Wt[c4 * 4 + 1][r] = v.y;
      Wt[c4 * 4 + 2][r] = v.z; Wt[c4 * 4 + 3][r] = v.w;
    }
    __syncthreads();
#pragma unroll 8
    for (int k = 0; k < KC; ++k) {
      const float4 av = *(const float4*)&At[k][tm * 4];
      const float4 wv = *(const float4*)&Wt[k][tn * 4];
      const float a[4] = {av.x, av.y, av.z, av.w};
      const float wr[4] = {wv.x, wv.y, wv.z, wv.w};
#pragma unroll
      for (int i = 0; i < 4; ++i)
#pragma unroll
        for (int j = 0; j < 4; ++j)
          acc[i][j] = fmaf(a[i], wr[j], acc[i][j]);
    }
  }
  // epilogue: bias + transposed scatter (exact magic div by 1020)
  float bv[4];
#pragma unroll
  for (int j = 0; j < 4; ++j)
    bv[j] = bih[n0 + tn * 4 + j] + bhh[n0 + tn * 4 + j];
#pragma unroll
  for (int i = 0; i < 4; ++i) {
    const int m  = m0 + tm * 4 + i;
    const int bb = (int)(((unsigned long long)m * 4311810306ULL) >> 42); // m/1020 exact
    const int t  = m - bb * TT;
    float* dst = xgT + ((size_t)bb * Ntot + n0 + tn * 4) * TT + t;
#pragma unroll
    for (int j = 0; j < 4; ++j) dst[(size_t)j * TT] = acc[i][j] + bv[j];
  }
}

// =====================================================================
// LSTM recurrence: one wave per batch element. Gate order i,f,g,o.
// H=32: lane holds gates {lane, lane+64}; H=16: lane holds gate {lane}.
// Whh rows in VGPRs; h broadcast via readlane; gate transpose via shfl_xor.
// xgT[b][g][t] streamed with 16-step double-buffered prefetch (4 float4 per
// stream in flight) — at 2 waves/CU nothing else hides the ~900cyc latency.
// =====================================================================
template <int H, bool FINAL>
__global__ __launch_bounds__(64) void lstm_kernel(
    const float* __restrict__ xgT, const float* __restrict__ Whh,
    float* __restrict__ hout) {
  constexpr int G   = 4 * H;
  constexpr int GPL = G / 64;  // 2 for H=32, 1 for H=16
  constexpr int KG  = H / 4;   // k-group size
  const int b    = blockIdx.x;
  const int lane = threadIdx.x;
  const int g0 = lane;
  const int g1 = lane + 64;

  float w0[H];
  float w1[GPL == 2 ? H : 1];
#pragma unroll
  for (int k = 0; k < H; ++k) {
    w0[k] = Whh[g0 * H + k];
    if constexpr (GPL == 2) w1[k] = Whh[g1 * H + k];
  }

  const float* p0 = xgT + ((size_t)b * G + g0) * TT;
  const float* p1 = xgT + ((size_t)b * G + (GPL == 2 ? g1 : g0)) * TT;

  float h = 0.f, c = 0.f;
  float4 cur0[4], cur1[4], nxt0[4], nxt1[4];
#pragma unroll
  for (int r = 0; r < 4; ++r) {
    cur0[r] = *(const float4*)(p0 + 4 * r);
    nxt0[r] = *(const float4*)(p0 + 16 + 4 * r);
    if constexpr (GPL == 2) {
      cur1[r] = *(const float4*)(p1 + 4 * r);
      nxt1[r] = *(const float4*)(p1 + 16 + 4 * r);
    }
  }

  for (int t16 = 0; t16 < TT; t16 += 16) {
#pragma unroll
    for (int r = 0; r < 4; ++r) {
      const int t4 = t16 + 4 * r;
      if (t4 >= TT) break;   // tail: TT=1020 = 63*16 + 12
#pragma unroll
      for (int s = 0; s < 4; ++s) {
        // recurrent matvec with 4-way split accumulators (short dep chains)
        float q0[4], q1[4];
        q0[0] = ((const float*)&cur0[r])[s]; q0[1] = 0.f; q0[2] = 0.f; q0[3] = 0.f;
        if constexpr (GPL == 2) {
          q1[0] = ((const float*)&cur1[r])[s]; q1[1] = 0.f; q1[2] = 0.f; q1[3] = 0.f;
        }
#pragma unroll
        for (int g = 0; g < 4; ++g)
#pragma unroll
          for (int k8 = 0; k8 < KG; ++k8) {
            const int k = g * KG + k8;
            const float hk =
                __uint_as_float(__builtin_amdgcn_readlane(__float_as_uint(h), k));
            q0[g] = fmaf(w0[k], hk, q0[g]);
            if constexpr (GPL == 2) q1[g] = fmaf(w1[k], hk, q1[g]);
          }
        const float acc0 = (q0[0] + q0[1]) + (q0[2] + q0[3]);
        float acc1 = 0.f;
        if constexpr (GPL == 2) acc1 = (q1[0] + q1[1]) + (q1[2] + q1[3]);

        // gather i,f,g,o raw gate values to every lane
        float iraw, fraw, graw, oraw;
        if constexpr (H == 32) {
          const float r0 = __shfl_xor(acc0, 32, 64);
          const float r1 = __shfl_xor(acc1, 32, 64);
          const bool hi = lane >= 32;
          iraw = hi ? r0 : acc0;
          fraw = hi ? acc0 : r0;
          graw = hi ? r1 : acc1;
          oraw = hi ? acc1 : r1;
        } else {
          const float x1 = __shfl_xor(acc0, 16, 64);
          const float x2 = __shfl_xor(acc0, 32, 64);
          const float x3 = __shfl_xor(acc0, 48, 64);
          const int q = lane >> 4;
          const float t0 = (q & 1) ? x1 : acc0;
          const float t1 = (q & 1) ? acc0 : x1;
          const float u0 = (q & 1) ? x3 : x2;
          const float u1 = (q & 1) ? x2 : x3;
          const bool hi2 = q >= 2;
          iraw = hi2 ? u0 : t0;
          fraw = hi2 ? u1 : t1;
          graw = hi2 ? t0 : u0;
          oraw = hi2 ? t1 : u1;
        }
        const float ig = fsig(iraw);
        const float fg = fsig(fraw);
        const float gg = ftanh(graw);
        const float og = fsig(oraw);
        c = fmaf(fg, c, ig * gg);
        h = og * ftanh(c);
        if constexpr (!FINAL) {
          if (lane < H) hout[((size_t)b * TT + (t4 + s)) * H + lane] = h;
        } else {
          if (t4 + s == TT - 1 && lane < H) hout[b * H + lane] = h;
        }
      }
    }
    // rotate double-buffer and prefetch t16+32 .. t16+47
#pragma unroll
    for (int r = 0; r < 4; ++r) {
      cur0[r] = nxt0[r];
      if constexpr (GPL == 2) cur1[r] = nxt1[r];
      const int tp = t16 + 32 + 4 * r;
      if (tp < TT) {
        nxt0[r] = *(const float4*)(p0 + tp);
        if constexpr (GPL == 2) nxt1[r] = *(const float4*)(p1 + tp);
      }
    }
  }
}

// =====================================================================
extern "C" void kernel_launch(void* const* d_in, const int* in_sizes, int n_in,
                              void* d_out, int out_size, void* d_ws, size_t ws_size,
                              hipStream_t stream) {
  const float* x      = (const float*)d_in[0];
  const float* conv_w = (const float*)d_in[1];
  const float* conv_b = (const float*)d_in[2];
  const float* Wih1   = (const float*)d_in[3];
  const float* Whh1   = (const float*)d_in[4];
  const float* bih1   = (const float*)d_in[5];
  const float* bhh1   = (const float*)d_in[6];
  const float* Wih2   = (const float*)d_in[7];
  const float* Whh2   = (const float*)d_in[8];
  const float* bih2   = (const float*)d_in[9];
  const float* bhh2   = (const float*)d_in[10];
  const float* Wih3   = (const float*)d_in[11];
  const float* Whh3   = (const float*)d_in[12];
  const float* bih3   = (const float*)d_in[13];
  const float* bhh3   = (const float*)d_in[14];
  float* out = (float*)d_out;
  float* ws  = (float*)d_ws;

  // workspace layout (floats); regions reused once dead:
  float* c    = ws;                    // 66,846,720  : conv out == seq (flat view)
  float* xgT1 = ws + 66846720;         // 66,846,720  : layer-1 gates, transposed
  float* h1   = ws + 133693440;        // 16,711,680  : layer-1 hidden
  float* xgT2 = c;                     // 33,423,360  : reuse conv region
  float* h2   = h1;                    //  8,355,840  : reuse h1 region
  float* xgT3 = xgT1;                  // 66,846,720  : reuse xgT1 region
  // total footprint: 601.6 MB

  conv_kernel<<<dim3(4, 4, BATCH), 256, 0, stream>>>(x, conv_w, conv_b, c);
  // seq is c reinterpreted as [B*1020][128] (the reference's .view quirk)
  gemm_xg<128><<<dim3(MM / 64, 2), 256, 0, stream>>>(c, Wih1, bih1, bhh1, xgT1, 128);
  lstm_kernel<32, false><<<BATCH, 64, 0, stream>>>(xgT1, Whh1, h1);
  gemm_xg<32><<<dim3(MM / 64, 1), 256, 0, stream>>>(h1, Wih2, bih2, bhh2, xgT2, 64);
  lstm_kernel<16, false><<<BATCH, 64, 0, stream>>>(xgT2, Whh2, h2);
  gemm_xg<16><<<dim3(MM / 64, 2), 256, 0, stream>>>(h2, Wih3, bih3, bhh3, xgT3, 128);
  lstm_kernel<32, true><<<BATCH, 64, 0, stream>>>(xgT3, Whh3, out);
}